// Round 10
// baseline (429.927 us; speedup 1.0000x reference)
//
#include <hip/hip_runtime.h>
#include <math.h>

// Problem: inputs (32,64,64,64) BCHW fp32, codebook (1024,64) fp32
// out: [loss][q_st 8388608][perp][one-hot 134217728] fp32
typedef _Float16 half8 __attribute__((ext_vector_type(8)));
typedef float f32x4 __attribute__((ext_vector_type(4)));

#define Q_OFF    1
#define PERP_OFF 8388609
#define OH_OFF   8388610
#define LOSS_N   8388608.0f
// DIAGNOSTIC ROUND: aligned memset from float 8388608 (byte 33554432,
// 256B-aligned) through buffer end; covers q_st[last]+perp+one-hot, all
// rewritten by k_compute/k2 afterwards.
#define MS_OFF_F  8388608
#define MS_BYTES  536870920ull

// ws byte layout:
// [0,4096)        cnorm (1024 f32)
// [4096,8192)     hist  (1024 int)
// [8192,12288)    partial (1024 f32)
// [16384,278528)  cb2: 64 tiles x 4KB; tile = 16 codes:
//                 [hi ks0 1KB | hi ks1 1KB | lo ks0 1KB | lo ks1 1KB],
//                 within each 1KB: code c (0..15) x 64B (dims g*8+i, g=0..3)
#define CB2_OFF_B 16384

__global__ __launch_bounds__(256) void k0_prep(const float* __restrict__ cb,
                                               float* __restrict__ cnorm,
                                               int* __restrict__ hist,
                                               char* __restrict__ cb2) {
  int k = blockIdx.x * 256 + threadIdx.x;   // grid=4 -> k in [0,1024)
  hist[k] = 0;
  const float* row = cb + (size_t)k * 64;
  const float4* r4 = (const float4*)row;
  float s = 0.f;
#pragma unroll
  for (int i = 0; i < 16; ++i) {
    float4 v = r4[i];
    s += v.x * v.x + v.y * v.y + v.z * v.z + v.w * v.w;
  }
  cnorm[k] = s;

  // fp16 hi/lo split, tile-contiguous layout for dense per-wave loads.
  int tile = k >> 4, c = k & 15;
  char* base = cb2 + tile * 4096;
#pragma unroll
  for (int d16 = 0; d16 < 8; ++d16) {
    half8 hh, ll;
#pragma unroll
    for (int i = 0; i < 8; ++i) {
      float v = row[d16 * 8 + i];
      _Float16 h = (_Float16)v;
      hh[i] = h;
      ll[i] = (_Float16)(v - (float)h);
    }
    int off = (d16 >> 2) * 1024 + c * 64 + (d16 & 3) * 16;  // ks | code | g
    *(half8*)(base + off) = hh;          // hi
    *(half8*)(base + 2048 + off) = ll;   // lo
  }
}

// DIAGNOSTIC: identical to round-9 k_compute except the code scan runs 4x
// (rolled loop, rotated order per pass -> no cross-pass load CSE; strict-<
// argmin is invariant under re-scanning, so outputs are bit-identical).
// Purpose: push this kernel's duration above the ~340us harness poison fills
// so its rocprof counters become visible, and let the total separate
// compute_solo from memset duration.
__global__ __launch_bounds__(256, 4) void k_compute(
    const float* __restrict__ in, const float* __restrict__ cb,
    const char* __restrict__ cb2, const float* __restrict__ cnorm,
    int* __restrict__ hist, float* __restrict__ partial,
    float* __restrict__ out) {
  __shared__ int bestk_s[128];
  __shared__ float red[256];

  const int tid = threadIdx.x;
  const int bid = blockIdx.x;
  const int b = bid >> 5;
  const int hw0 = (bid & 31) << 7;
  const int w = tid >> 6, l = tid & 63, q = l & 15, g = l >> 4;

  // A fragments: 2 point-tiles x 2 ksteps, fp16 hi/lo.
  // lane holds A[row=q][k = g*8+i (+32 for ks=1)]
  half8 ah[2][2], al[2][2];
  {
    const float* xb = in + ((size_t)b << 18);
#pragma unroll
    for (int a = 0; a < 2; ++a) {
      const int hw = hw0 + w * 32 + a * 16 + q;
#pragma unroll
      for (int ks = 0; ks < 2; ++ks) {
#pragma unroll
        for (int i = 0; i < 8; ++i) {
          float v = xb[((size_t)(ks * 32 + g * 8 + i) << 12) + hw];
          _Float16 h = (_Float16)v;
          ah[a][ks][i] = h;
          al[a][ks][i] = (_Float16)(v - (float)h);
        }
      }
    }
  }

  float bd0[4], bd1[4];
  int bk0[4], bk1[4];
#pragma unroll
  for (int j = 0; j < 4; ++j) { bd0[j] = bd1[j] = 3.4e38f; bk0[j] = bk1[j] = 0; }

  const int boff = q * 64 + g * 16;            // dense 1KB per wave-load

#pragma unroll 1
  for (int tb4 = 0; tb4 < 256; ++tb4) {
    const int tb = (tb4 + (tb4 >> 6)) & 63;    // pass r scans rotated by r
    const char* tbase = cb2 + tb * 4096 + boff;
    half8 bh0 = *(const half8*)(tbase);
    half8 bh1 = *(const half8*)(tbase + 1024);
    half8 bl0 = *(const half8*)(tbase + 2048);
    half8 bl1 = *(const half8*)(tbase + 3072);
    const int code = tb * 16 + q;
    const float cn = cnorm[code];
    const f32x4 z = {0.f, 0.f, 0.f, 0.f};
    // a = 0: dot = xh.ch + xl.ch + xh.cl  (two 3-chains for ILP)
    f32x4 s = __builtin_amdgcn_mfma_f32_16x16x32_f16(ah[0][0], bh0, z, 0, 0, 0);
    s = __builtin_amdgcn_mfma_f32_16x16x32_f16(al[0][0], bh0, s, 0, 0, 0);
    s = __builtin_amdgcn_mfma_f32_16x16x32_f16(ah[0][0], bl0, s, 0, 0, 0);
    f32x4 t = __builtin_amdgcn_mfma_f32_16x16x32_f16(ah[0][1], bh1, z, 0, 0, 0);
    t = __builtin_amdgcn_mfma_f32_16x16x32_f16(al[0][1], bh1, t, 0, 0, 0);
    t = __builtin_amdgcn_mfma_f32_16x16x32_f16(ah[0][1], bl1, t, 0, 0, 0);
    s = s + t;
#pragma unroll
    for (int j = 0; j < 4; ++j) {
      float d = fmaf(-2.f, s[j], cn);
      if (d < bd0[j]) { bd0[j] = d; bk0[j] = code; }
    }
    // a = 1
    f32x4 u = __builtin_amdgcn_mfma_f32_16x16x32_f16(ah[1][0], bh0, z, 0, 0, 0);
    u = __builtin_amdgcn_mfma_f32_16x16x32_f16(al[1][0], bh0, u, 0, 0, 0);
    u = __builtin_amdgcn_mfma_f32_16x16x32_f16(ah[1][0], bl0, u, 0, 0, 0);
    f32x4 v = __builtin_amdgcn_mfma_f32_16x16x32_f16(ah[1][1], bh1, z, 0, 0, 0);
    v = __builtin_amdgcn_mfma_f32_16x16x32_f16(al[1][1], bh1, v, 0, 0, 0);
    v = __builtin_amdgcn_mfma_f32_16x16x32_f16(ah[1][1], bl1, v, 0, 0, 0);
    u = u + v;
#pragma unroll
    for (int j = 0; j < 4; ++j) {
      float d = fmaf(-2.f, u[j], cn);
      if (d < bd1[j]) { bd1[j] = d; bk1[j] = code; }
    }
  }

  // Butterfly argmin across the 16 code-residues (q = lane&15).
  // Equal distances -> lower code index (reference: first-index argmax).
#pragma unroll
  for (int m = 1; m < 16; m <<= 1) {
#pragma unroll
    for (int j = 0; j < 4; ++j) {
      float od = __shfl_xor(bd0[j], m, 64);
      int ok = __shfl_xor(bk0[j], m, 64);
      if (od < bd0[j] || (od == bd0[j] && ok < bk0[j])) { bd0[j] = od; bk0[j] = ok; }
      od = __shfl_xor(bd1[j], m, 64);
      ok = __shfl_xor(bk1[j], m, 64);
      if (od < bd1[j] || (od == bd1[j] && ok < bk1[j])) { bd1[j] = od; bk1[j] = ok; }
    }
  }
  if (q == 0) {
#pragma unroll
    for (int j = 0; j < 4; ++j) {
      bestk_s[w * 32 + g * 4 + j] = bk0[j];          // a=0 tile
      bestk_s[w * 32 + 16 + g * 4 + j] = bk1[j];     // a=1 tile
    }
  }
  __syncthreads();

  // ---- Epilogue: one-hot 1.0s, hist, q_st, loss ----
  const int p = tid & 127, hf = tid >> 7;
  const int kq = bestk_s[p];
  if (hf == 0) {
    out[OH_OFF + ((size_t)b << 22) + ((size_t)kq << 12) + hw0 + p] = 1.0f;
    atomicAdd(&hist[kq], 1);   // integer: deterministic
  }
  float lsum = 0.f;
  {
    const float* xb = in + ((size_t)b << 18) + hw0 + p;
    float* yb = out + Q_OFF + ((size_t)b << 18) + hw0 + p;
    const float* qrow = cb + (size_t)kq * 64;
#pragma unroll
    for (int c = 0; c < 32; ++c) {
      const int cc = hf * 32 + c;
      float x = xb[(size_t)cc << 12];
      float f = qrow[cc] - x;
      lsum += f * f;
      yb[(size_t)cc << 12] = x + f;   // fl(x + fl(q-x)) as reference
    }
  }
  red[tid] = lsum;
  __syncthreads();
#pragma unroll
  for (int sft = 128; sft > 0; sft >>= 1) {
    if (tid < sft) red[tid] += red[tid + sft];
    __syncthreads();
  }
  if (tid == 0) partial[bid] = red[0];
}

__global__ __launch_bounds__(1024) void k2_finalize(const int* __restrict__ hist,
                                                    const float* __restrict__ partial,
                                                    float* __restrict__ out) {
  __shared__ float red[1024];
  int tid = threadIdx.x;

  // loss = 0.25 * mean((q-x)^2)
  red[tid] = partial[tid];
  __syncthreads();
  for (int s = 512; s > 0; s >>= 1) {
    if (tid < s) red[tid] += red[tid + s];
    __syncthreads();
  }
  if (tid == 0) out[0] = 0.25f * (red[0] / LOSS_N);
  __syncthreads();

  // perplexity = exp(-sum p*log(p+1e-10)), p = count / 2^17 (exact)
  float pr = (float)hist[tid] * (1.0f / 131072.0f);
  red[tid] = pr * logf(pr + 1e-10f);
  __syncthreads();
  for (int s = 512; s > 0; s >>= 1) {
    if (tid < s) red[tid] += red[tid + s];
    __syncthreads();
  }
  if (tid == 0) out[PERP_OFF] = expf(-red[0]);
}

extern "C" void kernel_launch(void* const* d_in, const int* in_sizes, int n_in,
                              void* d_out, int out_size, void* d_ws, size_t ws_size,
                              hipStream_t stream) {
  const float* in = (const float*)d_in[0];
  const float* cb = (const float*)d_in[1];
  float* out = (float*)d_out;

  float* cnorm   = (float*)d_ws;
  int*   hist    = (int*)d_ws + 1024;
  float* partial = (float*)d_ws + 2048;
  char*  cb2b    = (char*)d_ws + CB2_OFF_B;

  k0_prep<<<4, 256, 0, stream>>>(cb, cnorm, hist, cb2b);
  // 256B-ALIGNED memset (tests the misaligned-slow-path theory): covers
  // q_st[last]+perp+one-hot; all non-zero values rewritten downstream.
  hipMemsetAsync(out + MS_OFF_F, 0, MS_BYTES, stream);
  k_compute<<<1024, 256, 0, stream>>>(in, cb, cb2b, cnorm, hist, partial, out);
  k2_finalize<<<1, 1024, 0, stream>>>(hist, partial, out);
}

// Round 11
// 296.735 us; speedup vs baseline: 1.4489x; 1.4489x over previous
//
#include <hip/hip_runtime.h>
#include <math.h>

// Problem: inputs (32,64,64,64) BCHW fp32, codebook (1024,64) fp32
// out: [loss][q_st 8388608][perp][one-hot 134217728] fp32
typedef _Float16 half8 __attribute__((ext_vector_type(8)));
typedef float f32x4 __attribute__((ext_vector_type(4)));

#define NBLK     2048
#define Q_OFF    1
#define PERP_OFF 8388609
#define OH_OFF   8388610
#define LOSS_N   8388608.0f
// 256B-ALIGNED memset base (proven 7.3 TB/s in R10 vs 2.7 TB/s misaligned):
// covers q_st's last element + perp + one-hot; both rewritten downstream.
#define MS_OFF_F  8388608
#define MS_BYTES  536870920ull

// ws byte layout:
// [0,4096)        cnorm (1024 f32)
// [4096,8192)     hist  (1024 int)
// [8192,16384)    partial (2048 f32)
// [16384,278528)  cb2: 64 tiles x 4KB; tile = 16 codes:
//                 [hi ks0 1KB | hi ks1 1KB | lo ks0 1KB | lo ks1 1KB],
//                 within each 1KB: code c (0..15) x 64B (dims g*8+i, g=0..3)
#define CB2_OFF_B 16384

__global__ __launch_bounds__(256) void k0_prep(const float* __restrict__ cb,
                                               float* __restrict__ cnorm,
                                               int* __restrict__ hist,
                                               char* __restrict__ cb2) {
  int k = blockIdx.x * 256 + threadIdx.x;   // grid=4 -> k in [0,1024)
  hist[k] = 0;
  const float* row = cb + (size_t)k * 64;
  const float4* r4 = (const float4*)row;
  float s = 0.f;
#pragma unroll
  for (int i = 0; i < 16; ++i) {
    float4 v = r4[i];
    s += v.x * v.x + v.y * v.y + v.z * v.z + v.w * v.w;
  }
  cnorm[k] = s;

  // fp16 hi/lo split, tile-contiguous layout for dense per-wave loads.
  int tile = k >> 4, c = k & 15;
  char* base = cb2 + tile * 4096;
#pragma unroll
  for (int d16 = 0; d16 < 8; ++d16) {
    half8 hh, ll;
#pragma unroll
    for (int i = 0; i < 8; ++i) {
      float v = row[d16 * 8 + i];
      _Float16 h = (_Float16)v;
      hh[i] = h;
      ll[i] = (_Float16)(v - (float)h);
    }
    int off = (d16 >> 2) * 1024 + c * 64 + (d16 & 3) * 16;  // ks | code | g
    *(half8*)(base + off) = hh;          // hi
    *(half8*)(base + 2048 + off) = ll;   // lo
  }
}

// 2048 blocks x 4 waves; block = 64 points (b fixed, 64-wide hw window),
// wave = ONE 16-point MFMA A-tile scanning all 1024 codes in 64 tiles.
// vs R10: 2x blocks (target 6/CU -> 24 waves/CU, was 16) and manual 1-tile
// B-prefetch so the L2 load latency hides under a full tile of MFMA+VALU.
// dist = ||c||^2 - 2*x.c via 3-term fp16-split MFMA (exact argmin vs fp32,
// verified rounds 4-10). Memset precedes us; epilogue writes the 1.0s.
#define TILE_BODY(C0, C1, C2, C3, TB)                                          \
  do {                                                                         \
    const int code = (TB) * 16 + q;                                            \
    const float cn = cnorm[code];                                              \
    const f32x4 z = {0.f, 0.f, 0.f, 0.f};                                      \
    f32x4 s = __builtin_amdgcn_mfma_f32_16x16x32_f16(ah0, C0, z, 0, 0, 0);     \
    s = __builtin_amdgcn_mfma_f32_16x16x32_f16(al0, C0, s, 0, 0, 0);           \
    s = __builtin_amdgcn_mfma_f32_16x16x32_f16(ah0, C2, s, 0, 0, 0);           \
    f32x4 t = __builtin_amdgcn_mfma_f32_16x16x32_f16(ah1, C1, z, 0, 0, 0);     \
    t = __builtin_amdgcn_mfma_f32_16x16x32_f16(al1, C1, t, 0, 0, 0);           \
    t = __builtin_amdgcn_mfma_f32_16x16x32_f16(ah1, C3, t, 0, 0, 0);           \
    s = s + t;                                                                 \
    _Pragma("unroll") for (int j = 0; j < 4; ++j) {                            \
      float d = fmaf(-2.f, s[j], cn);                                          \
      if (d < bd[j]) { bd[j] = d; bk[j] = code; }                              \
    }                                                                          \
  } while (0)

__global__ __launch_bounds__(256, 6) void k_compute(
    const float* __restrict__ in, const float* __restrict__ cb,
    const char* __restrict__ cb2, const float* __restrict__ cnorm,
    int* __restrict__ hist, float* __restrict__ partial,
    float* __restrict__ out) {
  __shared__ int bestk_s[64];
  __shared__ float red[256];

  const int tid = threadIdx.x;
  const int bid = blockIdx.x;
  const int b = bid >> 6;               // 64 blocks per batch
  const int hw0 = (bid & 63) << 6;      // 64-point window
  const int w = tid >> 6, l = tid & 63, q = l & 15, g = l >> 4;

  // A fragments: one 16-point tile, 2 ksteps, fp16 hi/lo.
  // lane holds A[row=q][k = g*8+i (+32 for ks=1)]
  half8 ah0, ah1, al0, al1;
  {
    const float* xb = in + ((size_t)b << 18);
    const int hw = hw0 + w * 16 + q;
#pragma unroll
    for (int i = 0; i < 8; ++i) {
      float v0 = xb[((size_t)(g * 8 + i) << 12) + hw];
      _Float16 h0 = (_Float16)v0;
      ah0[i] = h0; al0[i] = (_Float16)(v0 - (float)h0);
      float v1 = xb[((size_t)(32 + g * 8 + i) << 12) + hw];
      _Float16 h1 = (_Float16)v1;
      ah1[i] = h1; al1[i] = (_Float16)(v1 - (float)h1);
    }
  }

  float bd[4];
  int bk[4];
#pragma unroll
  for (int j = 0; j < 4; ++j) { bd[j] = 3.4e38f; bk[j] = 0; }

  const int boff = q * 64 + g * 16;            // dense 1KB per wave-load

  // Software-pipelined scan: prefetch tile tb+1's B-frags before computing tb.
  const char* t0 = cb2 + boff;
  half8 c0 = *(const half8*)(t0);
  half8 c1 = *(const half8*)(t0 + 1024);
  half8 c2 = *(const half8*)(t0 + 2048);
  half8 c3 = *(const half8*)(t0 + 3072);
  for (int tb = 0; tb < 63; ++tb) {
    const char* nt = cb2 + (tb + 1) * 4096 + boff;
    half8 n0 = *(const half8*)(nt);
    half8 n1 = *(const half8*)(nt + 1024);
    half8 n2 = *(const half8*)(nt + 2048);
    half8 n3 = *(const half8*)(nt + 3072);
    TILE_BODY(c0, c1, c2, c3, tb);
    c0 = n0; c1 = n1; c2 = n2; c3 = n3;
  }
  TILE_BODY(c0, c1, c2, c3, 63);

  // Butterfly argmin across the 16 code-residues (q = lane&15).
  // Equal distances -> lower code index (reference: first-index argmax).
#pragma unroll
  for (int m = 1; m < 16; m <<= 1) {
#pragma unroll
    for (int j = 0; j < 4; ++j) {
      float od = __shfl_xor(bd[j], m, 64);
      int ok = __shfl_xor(bk[j], m, 64);
      if (od < bd[j] || (od == bd[j] && ok < bk[j])) { bd[j] = od; bk[j] = ok; }
    }
  }
  if (q == 0) {
#pragma unroll
    for (int j = 0; j < 4; ++j) bestk_s[w * 16 + g * 4 + j] = bk[j];
  }
  __syncthreads();

  // ---- Epilogue: one-hot 1.0s, hist, q_st, loss ----
  const int p = tid & 63, hf = tid >> 6;       // hf = 0..3, 16 channels each
  const int kq = bestk_s[p];
  if (hf == 0) {
    out[OH_OFF + ((size_t)b << 22) + ((size_t)kq << 12) + hw0 + p] = 1.0f;
    atomicAdd(&hist[kq], 1);   // integer: deterministic
  }
  float lsum = 0.f;
  {
    const float* xb = in + ((size_t)b << 18) + hw0 + p;
    float* yb = out + Q_OFF + ((size_t)b << 18) + hw0 + p;
    const float* qrow = cb + (size_t)kq * 64;
#pragma unroll
    for (int c = 0; c < 16; ++c) {
      const int cc = hf * 16 + c;
      float x = xb[(size_t)cc << 12];
      float f = qrow[cc] - x;
      lsum += f * f;
      yb[(size_t)cc << 12] = x + f;   // fl(x + fl(q-x)) as reference
    }
  }
  red[tid] = lsum;
  __syncthreads();
#pragma unroll
  for (int sft = 128; sft > 0; sft >>= 1) {
    if (tid < sft) red[tid] += red[tid + sft];
    __syncthreads();
  }
  if (tid == 0) partial[bid] = red[0];
}

__global__ __launch_bounds__(1024) void k2_finalize(const int* __restrict__ hist,
                                                    const float* __restrict__ partial,
                                                    float* __restrict__ out) {
  __shared__ float red[1024];
  int tid = threadIdx.x;

  // loss = 0.25 * mean((q-x)^2)  (2048 block partials)
  red[tid] = partial[tid] + partial[tid + 1024];
  __syncthreads();
  for (int s = 512; s > 0; s >>= 1) {
    if (tid < s) red[tid] += red[tid + s];
    __syncthreads();
  }
  if (tid == 0) out[0] = 0.25f * (red[0] / LOSS_N);
  __syncthreads();

  // perplexity = exp(-sum p*log(p+1e-10)), p = count / 2^17 (exact)
  float pr = (float)hist[tid] * (1.0f / 131072.0f);
  red[tid] = pr * logf(pr + 1e-10f);
  __syncthreads();
  for (int s = 512; s > 0; s >>= 1) {
    if (tid < s) red[tid] += red[tid + s];
    __syncthreads();
  }
  if (tid == 0) out[PERP_OFF] = expf(-red[0]);
}

extern "C" void kernel_launch(void* const* d_in, const int* in_sizes, int n_in,
                              void* d_out, int out_size, void* d_ws, size_t ws_size,
                              hipStream_t stream) {
  const float* in = (const float*)d_in[0];
  const float* cb = (const float*)d_in[1];
  float* out = (float*)d_out;

  float* cnorm   = (float*)d_ws;
  int*   hist    = (int*)d_ws + 1024;
  float* partial = (float*)d_ws + 2048;
  char*  cb2b    = (char*)d_ws + CB2_OFF_B;

  k0_prep<<<4, 256, 0, stream>>>(cb, cnorm, hist, cb2b);
  hipMemsetAsync(out + MS_OFF_F, 0, MS_BYTES, stream);   // aligned fast path
  k_compute<<<NBLK, 256, 0, stream>>>(in, cb, cb2b, cnorm, hist, partial, out);
  k2_finalize<<<1, 1024, 0, stream>>>(hist, partial, out);
}

// Round 12
// 291.166 us; speedup vs baseline: 1.4766x; 1.0191x over previous
//
#include <hip/hip_runtime.h>
#include <math.h>

// Problem: inputs (32,64,64,64) BCHW fp32, codebook (1024,64) fp32
// out: [loss][q_st 8388608][perp][one-hot 134217728] fp32
typedef _Float16 half8 __attribute__((ext_vector_type(8)));
typedef float f32x4 __attribute__((ext_vector_type(4)));

#define Q_OFF    1
#define PERP_OFF 8388609
#define OH_OFF   8388610
#define LOSS_N   8388608.0f
// 256B-aligned fill base (float 8388608): covers q_st last elem + perp +
// one-hot; non-zero values rewritten downstream by k_compute / k2.
#define MS_OFF_F  8388608
#define FILL_N4   33554432ull   // float4 count from MS_OFF_F
#define FILL_G    524288ull     // 2048 blocks * 256 threads

// ws byte layout:
// [0,4096)        cnorm (1024 f32)
// [4096,8192)     hist  (1024 int)
// [8192,12288)    partial (1024 f32)
// [16384,278528)  cb2: 64 tiles x 4KB; tile = 16 codes:
//                 [hi ks0 1KB | hi ks1 1KB | lo ks0 1KB | lo ks1 1KB],
//                 within each 1KB: code c (0..15) x 64B (dims g*8+i, g=0..3)
#define CB2_OFF_B 16384

__global__ __launch_bounds__(256) void k0_prep(const float* __restrict__ cb,
                                               float* __restrict__ cnorm,
                                               int* __restrict__ hist,
                                               char* __restrict__ cb2) {
  int k = blockIdx.x * 256 + threadIdx.x;   // grid=4 -> k in [0,1024)
  hist[k] = 0;
  const float* row = cb + (size_t)k * 64;
  const float4* r4 = (const float4*)row;
  float s = 0.f;
#pragma unroll
  for (int i = 0; i < 16; ++i) {
    float4 v = r4[i];
    s += v.x * v.x + v.y * v.y + v.z * v.z + v.w * v.w;
  }
  cnorm[k] = s;

  // fp16 hi/lo split, tile-contiguous layout for dense per-wave loads.
  int tile = k >> 4, c = k & 15;
  char* base = cb2 + tile * 4096;
#pragma unroll
  for (int d16 = 0; d16 < 8; ++d16) {
    half8 hh, ll;
#pragma unroll
    for (int i = 0; i < 8; ++i) {
      float v = row[d16 * 8 + i];
      _Float16 h = (_Float16)v;
      hh[i] = h;
      ll[i] = (_Float16)(v - (float)h);
    }
    int off = (d16 >> 2) * 1024 + c * 64 + (d16 & 3) * 16;  // ks | code | g
    *(half8*)(base + off) = hh;          // hi
    *(half8*)(base + 2048 + off) = ll;   // lo
  }
}

// GRID-STRIDE zero-fill (the fillBufferAligned pattern): at step i the ENTIRE
// grid writes one contiguous 8MB frontier (float4 index gid + i*524288) —
// one marching DRAM window instead of 512-2048 scattered per-block streams
// (the R5-R8 hand-fills, all ~2.2-2.9 TB/s). Tests whether frontier
// contiguity is the 6.7 TB/s recipe.
__global__ __launch_bounds__(256) void k_fill_gs(float* __restrict__ out) {
  const size_t gid = (size_t)blockIdx.x * 256 + threadIdx.x;  // [0, 524288)
  float4* base = (float4*)(out + MS_OFF_F);
  const float4 z4 = make_float4(0.f, 0.f, 0.f, 0.f);
#pragma unroll 8
  for (int i = 0; i < 64; ++i)
    base[gid + (size_t)i * FILL_G] = z4;
  if (gid == 0) {   // 2-float tail of the region
    out[MS_OFF_F + 134217728] = 0.f;
    out[MS_OFF_F + 134217729] = 0.f;
  }
}

// VERBATIM round-9 k_compute (prof-pinned 88us, 44 VGPR): block = 256 thr
// (4 waves) = 128 points; wave = 2 MFMA A-tiles scanning all 1024 codes in 64
// tiles, B-frags from L2. dist = ||c||^2 - 2*x.c via 3-term fp16-split MFMA
// (exact argmin vs fp32, verified rounds 4-11). Epilogue writes 1.0s, hist,
// q_st, loss partials.
__global__ __launch_bounds__(256, 4) void k_compute(
    const float* __restrict__ in, const float* __restrict__ cb,
    const char* __restrict__ cb2, const float* __restrict__ cnorm,
    int* __restrict__ hist, float* __restrict__ partial,
    float* __restrict__ out) {
  __shared__ int bestk_s[128];
  __shared__ float red[256];

  const int tid = threadIdx.x;
  const int bid = blockIdx.x;
  const int b = bid >> 5;
  const int hw0 = (bid & 31) << 7;
  const int w = tid >> 6, l = tid & 63, q = l & 15, g = l >> 4;

  half8 ah[2][2], al[2][2];
  {
    const float* xb = in + ((size_t)b << 18);
#pragma unroll
    for (int a = 0; a < 2; ++a) {
      const int hw = hw0 + w * 32 + a * 16 + q;
#pragma unroll
      for (int ks = 0; ks < 2; ++ks) {
#pragma unroll
        for (int i = 0; i < 8; ++i) {
          float v = xb[((size_t)(ks * 32 + g * 8 + i) << 12) + hw];
          _Float16 h = (_Float16)v;
          ah[a][ks][i] = h;
          al[a][ks][i] = (_Float16)(v - (float)h);
        }
      }
    }
  }

  float bd0[4], bd1[4];
  int bk0[4], bk1[4];
#pragma unroll
  for (int j = 0; j < 4; ++j) { bd0[j] = bd1[j] = 3.4e38f; bk0[j] = bk1[j] = 0; }

  const int boff = q * 64 + g * 16;            // dense 1KB per wave-load

  for (int tb = 0; tb < 64; ++tb) {
    const char* tbase = cb2 + tb * 4096 + boff;
    half8 bh0 = *(const half8*)(tbase);
    half8 bh1 = *(const half8*)(tbase + 1024);
    half8 bl0 = *(const half8*)(tbase + 2048);
    half8 bl1 = *(const half8*)(tbase + 3072);
    const int code = tb * 16 + q;
    const float cn = cnorm[code];
    const f32x4 z = {0.f, 0.f, 0.f, 0.f};
    // a = 0: dot = xh.ch + xl.ch + xh.cl  (two 3-chains for ILP)
    f32x4 s = __builtin_amdgcn_mfma_f32_16x16x32_f16(ah[0][0], bh0, z, 0, 0, 0);
    s = __builtin_amdgcn_mfma_f32_16x16x32_f16(al[0][0], bh0, s, 0, 0, 0);
    s = __builtin_amdgcn_mfma_f32_16x16x32_f16(ah[0][0], bl0, s, 0, 0, 0);
    f32x4 t = __builtin_amdgcn_mfma_f32_16x16x32_f16(ah[0][1], bh1, z, 0, 0, 0);
    t = __builtin_amdgcn_mfma_f32_16x16x32_f16(al[0][1], bh1, t, 0, 0, 0);
    t = __builtin_amdgcn_mfma_f32_16x16x32_f16(ah[0][1], bl1, t, 0, 0, 0);
    s = s + t;
#pragma unroll
    for (int j = 0; j < 4; ++j) {
      float d = fmaf(-2.f, s[j], cn);
      if (d < bd0[j]) { bd0[j] = d; bk0[j] = code; }
    }
    // a = 1
    f32x4 u = __builtin_amdgcn_mfma_f32_16x16x32_f16(ah[1][0], bh0, z, 0, 0, 0);
    u = __builtin_amdgcn_mfma_f32_16x16x32_f16(al[1][0], bh0, u, 0, 0, 0);
    u = __builtin_amdgcn_mfma_f32_16x16x32_f16(ah[1][0], bl0, u, 0, 0, 0);
    f32x4 v = __builtin_amdgcn_mfma_f32_16x16x32_f16(ah[1][1], bh1, z, 0, 0, 0);
    v = __builtin_amdgcn_mfma_f32_16x16x32_f16(al[1][1], bh1, v, 0, 0, 0);
    v = __builtin_amdgcn_mfma_f32_16x16x32_f16(ah[1][1], bl1, v, 0, 0, 0);
    u = u + v;
#pragma unroll
    for (int j = 0; j < 4; ++j) {
      float d = fmaf(-2.f, u[j], cn);
      if (d < bd1[j]) { bd1[j] = d; bk1[j] = code; }
    }
  }

  // Butterfly argmin across the 16 code-residues (q = lane&15).
#pragma unroll
  for (int m = 1; m < 16; m <<= 1) {
#pragma unroll
    for (int j = 0; j < 4; ++j) {
      float od = __shfl_xor(bd0[j], m, 64);
      int ok = __shfl_xor(bk0[j], m, 64);
      if (od < bd0[j] || (od == bd0[j] && ok < bk0[j])) { bd0[j] = od; bk0[j] = ok; }
      od = __shfl_xor(bd1[j], m, 64);
      ok = __shfl_xor(bk1[j], m, 64);
      if (od < bd1[j] || (od == bd1[j] && ok < bk1[j])) { bd1[j] = od; bk1[j] = ok; }
    }
  }
  if (q == 0) {
#pragma unroll
    for (int j = 0; j < 4; ++j) {
      bestk_s[w * 32 + g * 4 + j] = bk0[j];          // a=0 tile
      bestk_s[w * 32 + 16 + g * 4 + j] = bk1[j];     // a=1 tile
    }
  }
  __syncthreads();

  // ---- Epilogue: one-hot 1.0s, hist, q_st, loss ----
  const int p = tid & 127, hf = tid >> 7;
  const int kq = bestk_s[p];
  if (hf == 0) {
    out[OH_OFF + ((size_t)b << 22) + ((size_t)kq << 12) + hw0 + p] = 1.0f;
    atomicAdd(&hist[kq], 1);   // integer: deterministic
  }
  float lsum = 0.f;
  {
    const float* xb = in + ((size_t)b << 18) + hw0 + p;
    float* yb = out + Q_OFF + ((size_t)b << 18) + hw0 + p;
    const float* qrow = cb + (size_t)kq * 64;
#pragma unroll
    for (int c = 0; c < 32; ++c) {
      const int cc = hf * 32 + c;
      float x = xb[(size_t)cc << 12];
      float f = qrow[cc] - x;
      lsum += f * f;
      yb[(size_t)cc << 12] = x + f;   // fl(x + fl(q-x)) as reference
    }
  }
  red[tid] = lsum;
  __syncthreads();
#pragma unroll
  for (int sft = 128; sft > 0; sft >>= 1) {
    if (tid < sft) red[tid] += red[tid + sft];
    __syncthreads();
  }
  if (tid == 0) partial[bid] = red[0];
}

__global__ __launch_bounds__(1024) void k2_finalize(const int* __restrict__ hist,
                                                    const float* __restrict__ partial,
                                                    float* __restrict__ out) {
  __shared__ float red[1024];
  int tid = threadIdx.x;

  // loss = 0.25 * mean((q-x)^2)
  red[tid] = partial[tid];
  __syncthreads();
  for (int s = 512; s > 0; s >>= 1) {
    if (tid < s) red[tid] += red[tid + s];
    __syncthreads();
  }
  if (tid == 0) out[0] = 0.25f * (red[0] / LOSS_N);
  __syncthreads();

  // perplexity = exp(-sum p*log(p+1e-10)), p = count / 2^17 (exact)
  float pr = (float)hist[tid] * (1.0f / 131072.0f);
  red[tid] = pr * logf(pr + 1e-10f);
  __syncthreads();
  for (int s = 512; s > 0; s >>= 1) {
    if (tid < s) red[tid] += red[tid + s];
    __syncthreads();
  }
  if (tid == 0) out[PERP_OFF] = expf(-red[0]);
}

extern "C" void kernel_launch(void* const* d_in, const int* in_sizes, int n_in,
                              void* d_out, int out_size, void* d_ws, size_t ws_size,
                              hipStream_t stream) {
  const float* in = (const float*)d_in[0];
  const float* cb = (const float*)d_in[1];
  float* out = (float*)d_out;

  float* cnorm   = (float*)d_ws;
  int*   hist    = (int*)d_ws + 1024;
  float* partial = (float*)d_ws + 2048;
  char*  cb2b    = (char*)d_ws + CB2_OFF_B;

  k0_prep<<<4, 256, 0, stream>>>(cb, cnorm, hist, cb2b);
  k_fill_gs<<<2048, 256, 0, stream>>>(out);
  k_compute<<<1024, 256, 0, stream>>>(in, cb, cb2b, cnorm, hist, partial, out);
  k2_finalize<<<1, 1024, 0, stream>>>(hist, partial, out);
}

// Round 13
// 263.458 us; speedup vs baseline: 1.6319x; 1.1052x over previous
//
#include <hip/hip_runtime.h>
#include <math.h>

// Problem: inputs (32,64,64,64) BCHW fp32, codebook (1024,64) fp32
// out: [loss][q_st 8388608][perp][one-hot 134217728] fp32
typedef _Float16 half8 __attribute__((ext_vector_type(8)));
typedef float f32x4 __attribute__((ext_vector_type(4)));

#define Q_OFF    1
#define PERP_OFF 8388609
#define OH_OFF   8388610
#define LOSS_N   8388608.0f
// 256B-ALIGNED memset base (proven ~7.5 TB/s in R10; misaligned base runs the
// 2.7 TB/s slow path): covers q_st's last element + perp + one-hot, all
// rewritten downstream by k_compute / k2.
#define MS_OFF_F  8388608
#define MS_BYTES  536870920ull

// ws byte layout:
// [0,4096)        cnorm (1024 f32)
// [4096,8192)     hist  (1024 int)
// [8192,12288)    partial (1024 f32)
// [16384,278528)  cb2: 64 tiles x 4KB; tile = 16 codes:
//                 [hi ks0 1KB | hi ks1 1KB | lo ks0 1KB | lo ks1 1KB],
//                 within each 1KB: code c (0..15) x 64B (dims g*8+i, g=0..3)
#define CB2_OFF_B 16384

__global__ __launch_bounds__(256) void k0_prep(const float* __restrict__ cb,
                                               float* __restrict__ cnorm,
                                               int* __restrict__ hist,
                                               char* __restrict__ cb2) {
  int k = blockIdx.x * 256 + threadIdx.x;   // grid=4 -> k in [0,1024)
  hist[k] = 0;
  const float* row = cb + (size_t)k * 64;
  const float4* r4 = (const float4*)row;
  float s = 0.f;
#pragma unroll
  for (int i = 0; i < 16; ++i) {
    float4 v = r4[i];
    s += v.x * v.x + v.y * v.y + v.z * v.z + v.w * v.w;
  }
  cnorm[k] = s;

  // fp16 hi/lo split, tile-contiguous layout for dense per-wave loads.
  int tile = k >> 4, c = k & 15;
  char* base = cb2 + tile * 4096;
#pragma unroll
  for (int d16 = 0; d16 < 8; ++d16) {
    half8 hh, ll;
#pragma unroll
    for (int i = 0; i < 8; ++i) {
      float v = row[d16 * 8 + i];
      _Float16 h = (_Float16)v;
      hh[i] = h;
      ll[i] = (_Float16)(v - (float)h);
    }
    int off = (d16 >> 2) * 1024 + c * 64 + (d16 & 3) * 16;  // ks | code | g
    *(half8*)(base + off) = hh;          // hi
    *(half8*)(base + 2048 + off) = ll;   // lo
  }
}

// VERBATIM round-9 k_compute (prof-pinned 88us, 44 VGPR): block = 256 thr
// (4 waves) = 128 points; wave = 2 MFMA A-tiles scanning all 1024 codes in 64
// tiles, B-frags from L2. dist = ||c||^2 - 2*x.c via 3-term fp16-split MFMA
// (exact argmin vs fp32, verified rounds 4-12). Epilogue writes 1.0s, hist,
// q_st, loss partials.
__global__ __launch_bounds__(256, 4) void k_compute(
    const float* __restrict__ in, const float* __restrict__ cb,
    const char* __restrict__ cb2, const float* __restrict__ cnorm,
    int* __restrict__ hist, float* __restrict__ partial,
    float* __restrict__ out) {
  __shared__ int bestk_s[128];
  __shared__ float red[256];

  const int tid = threadIdx.x;
  const int bid = blockIdx.x;
  const int b = bid >> 5;
  const int hw0 = (bid & 31) << 7;
  const int w = tid >> 6, l = tid & 63, q = l & 15, g = l >> 4;

  half8 ah[2][2], al[2][2];
  {
    const float* xb = in + ((size_t)b << 18);
#pragma unroll
    for (int a = 0; a < 2; ++a) {
      const int hw = hw0 + w * 32 + a * 16 + q;
#pragma unroll
      for (int ks = 0; ks < 2; ++ks) {
#pragma unroll
        for (int i = 0; i < 8; ++i) {
          float v = xb[((size_t)(ks * 32 + g * 8 + i) << 12) + hw];
          _Float16 h = (_Float16)v;
          ah[a][ks][i] = h;
          al[a][ks][i] = (_Float16)(v - (float)h);
        }
      }
    }
  }

  float bd0[4], bd1[4];
  int bk0[4], bk1[4];
#pragma unroll
  for (int j = 0; j < 4; ++j) { bd0[j] = bd1[j] = 3.4e38f; bk0[j] = bk1[j] = 0; }

  const int boff = q * 64 + g * 16;            // dense 1KB per wave-load

  for (int tb = 0; tb < 64; ++tb) {
    const char* tbase = cb2 + tb * 4096 + boff;
    half8 bh0 = *(const half8*)(tbase);
    half8 bh1 = *(const half8*)(tbase + 1024);
    half8 bl0 = *(const half8*)(tbase + 2048);
    half8 bl1 = *(const half8*)(tbase + 3072);
    const int code = tb * 16 + q;
    const float cn = cnorm[code];
    const f32x4 z = {0.f, 0.f, 0.f, 0.f};
    // a = 0: dot = xh.ch + xl.ch + xh.cl  (two 3-chains for ILP)
    f32x4 s = __builtin_amdgcn_mfma_f32_16x16x32_f16(ah[0][0], bh0, z, 0, 0, 0);
    s = __builtin_amdgcn_mfma_f32_16x16x32_f16(al[0][0], bh0, s, 0, 0, 0);
    s = __builtin_amdgcn_mfma_f32_16x16x32_f16(ah[0][0], bl0, s, 0, 0, 0);
    f32x4 t = __builtin_amdgcn_mfma_f32_16x16x32_f16(ah[0][1], bh1, z, 0, 0, 0);
    t = __builtin_amdgcn_mfma_f32_16x16x32_f16(al[0][1], bh1, t, 0, 0, 0);
    t = __builtin_amdgcn_mfma_f32_16x16x32_f16(ah[0][1], bl1, t, 0, 0, 0);
    s = s + t;
#pragma unroll
    for (int j = 0; j < 4; ++j) {
      float d = fmaf(-2.f, s[j], cn);
      if (d < bd0[j]) { bd0[j] = d; bk0[j] = code; }
    }
    // a = 1
    f32x4 u = __builtin_amdgcn_mfma_f32_16x16x32_f16(ah[1][0], bh0, z, 0, 0, 0);
    u = __builtin_amdgcn_mfma_f32_16x16x32_f16(al[1][0], bh0, u, 0, 0, 0);
    u = __builtin_amdgcn_mfma_f32_16x16x32_f16(ah[1][0], bl0, u, 0, 0, 0);
    f32x4 v = __builtin_amdgcn_mfma_f32_16x16x32_f16(ah[1][1], bh1, z, 0, 0, 0);
    v = __builtin_amdgcn_mfma_f32_16x16x32_f16(al[1][1], bh1, v, 0, 0, 0);
    v = __builtin_amdgcn_mfma_f32_16x16x32_f16(ah[1][1], bl1, v, 0, 0, 0);
    u = u + v;
#pragma unroll
    for (int j = 0; j < 4; ++j) {
      float d = fmaf(-2.f, u[j], cn);
      if (d < bd1[j]) { bd1[j] = d; bk1[j] = code; }
    }
  }

  // Butterfly argmin across the 16 code-residues (q = lane&15).
  // Equal distances -> lower code index (reference: first-index argmax).
#pragma unroll
  for (int m = 1; m < 16; m <<= 1) {
#pragma unroll
    for (int j = 0; j < 4; ++j) {
      float od = __shfl_xor(bd0[j], m, 64);
      int ok = __shfl_xor(bk0[j], m, 64);
      if (od < bd0[j] || (od == bd0[j] && ok < bk0[j])) { bd0[j] = od; bk0[j] = ok; }
      od = __shfl_xor(bd1[j], m, 64);
      ok = __shfl_xor(bk1[j], m, 64);
      if (od < bd1[j] || (od == bd1[j] && ok < bk1[j])) { bd1[j] = od; bk1[j] = ok; }
    }
  }
  if (q == 0) {
#pragma unroll
    for (int j = 0; j < 4; ++j) {
      bestk_s[w * 32 + g * 4 + j] = bk0[j];          // a=0 tile
      bestk_s[w * 32 + 16 + g * 4 + j] = bk1[j];     // a=1 tile
    }
  }
  __syncthreads();

  // ---- Epilogue: one-hot 1.0s, hist, q_st, loss ----
  const int p = tid & 127, hf = tid >> 7;
  const int kq = bestk_s[p];
  if (hf == 0) {
    out[OH_OFF + ((size_t)b << 22) + ((size_t)kq << 12) + hw0 + p] = 1.0f;
    atomicAdd(&hist[kq], 1);   // integer: deterministic
  }
  float lsum = 0.f;
  {
    const float* xb = in + ((size_t)b << 18) + hw0 + p;
    float* yb = out + Q_OFF + ((size_t)b << 18) + hw0 + p;
    const float* qrow = cb + (size_t)kq * 64;
#pragma unroll
    for (int c = 0; c < 32; ++c) {
      const int cc = hf * 32 + c;
      float x = xb[(size_t)cc << 12];
      float f = qrow[cc] - x;
      lsum += f * f;
      yb[(size_t)cc << 12] = x + f;   // fl(x + fl(q-x)) as reference
    }
  }
  red[tid] = lsum;
  __syncthreads();
#pragma unroll
  for (int sft = 128; sft > 0; sft >>= 1) {
    if (tid < sft) red[tid] += red[tid + sft];
    __syncthreads();
  }
  if (tid == 0) partial[bid] = red[0];
}

__global__ __launch_bounds__(1024) void k2_finalize(const int* __restrict__ hist,
                                                    const float* __restrict__ partial,
                                                    float* __restrict__ out) {
  __shared__ float red[1024];
  int tid = threadIdx.x;

  // loss = 0.25 * mean((q-x)^2)
  red[tid] = partial[tid];
  __syncthreads();
  for (int s = 512; s > 0; s >>= 1) {
    if (tid < s) red[tid] += red[tid + s];
    __syncthreads();
  }
  if (tid == 0) out[0] = 0.25f * (red[0] / LOSS_N);
  __syncthreads();

  // perplexity = exp(-sum p*log(p+1e-10)), p = count / 2^17 (exact)
  float pr = (float)hist[tid] * (1.0f / 131072.0f);
  red[tid] = pr * logf(pr + 1e-10f);
  __syncthreads();
  for (int s = 512; s > 0; s >>= 1) {
    if (tid < s) red[tid] += red[tid + s];
    __syncthreads();
  }
  if (tid == 0) out[PERP_OFF] = expf(-red[0]);
}

extern "C" void kernel_launch(void* const* d_in, const int* in_sizes, int n_in,
                              void* d_out, int out_size, void* d_ws, size_t ws_size,
                              hipStream_t stream) {
  const float* in = (const float*)d_in[0];
  const float* cb = (const float*)d_in[1];
  float* out = (float*)d_out;

  float* cnorm   = (float*)d_ws;
  int*   hist    = (int*)d_ws + 1024;
  float* partial = (float*)d_ws + 2048;
  char*  cb2b    = (char*)d_ws + CB2_OFF_B;

  k0_prep<<<4, 256, 0, stream>>>(cb, cnorm, hist, cb2b);
  hipMemsetAsync(out + MS_OFF_F, 0, MS_BYTES, stream);   // aligned fast path
  k_compute<<<1024, 256, 0, stream>>>(in, cb, cb2b, cnorm, hist, partial, out);
  k2_finalize<<<1, 1024, 0, stream>>>(hist, partial, out);
}